// Round 2
// baseline (7053.242 us; speedup 1.0000x reference)
//
#include <hip/hip_runtime.h>
#include <hip/hip_bf16.h>
#include <hip/hip_cooperative_groups.h>
#include <math.h>

namespace cg = cooperative_groups;

#define B_ 32
#define T_ 64
#define S_ 128
#define V_ 32000
#define E_ 256
#define U_ 1024

#define NB_ 144   // 80 qz-tiles + 64 gate-tiles; blocks 0..31 also run attention

typedef __bf16 bf16_t;
typedef __bf16 bf16x8 __attribute__((ext_vector_type(8)));
typedef float f32x4 __attribute__((ext_vector_type(4)));

__device__ __forceinline__ float sigm(float x) { return 1.f / (1.f + expf(-x)); }
__device__ __forceinline__ float tanh_fast(float x) {
    float e = __expf(2.f * x);                 // inf-safe: e=inf -> 1 ; e=0 -> -1
    return 1.f - __fdividef(2.f, e + 1.f);
}

__device__ __forceinline__ bf16x8 cvt8(const float* p) {
    float4 f0 = *(const float4*)p;
    float4 f1 = *(const float4*)(p + 4);
    bf16x8 v;
    v[0] = (bf16_t)f0.x; v[1] = (bf16_t)f0.y; v[2] = (bf16_t)f0.z; v[3] = (bf16_t)f0.w;
    v[4] = (bf16_t)f1.x; v[5] = (bf16_t)f1.y; v[6] = (bf16_t)f1.z; v[7] = (bf16_t)f1.w;
    return v;
}

// ---------------- init: h,c from h0,c0 ----------------
__global__ void k_init(const float* h0, const float* c0, bf16_t* h_bf, float* c_f) {
    int i = blockIdx.x * 256 + threadIdx.x;   // 32*1024
    h_bf[i] = (bf16_t)h0[i];
    c_f[i] = c0[i];
}

// ---------------- embed: x_all[t][b][e] = emb[tokens[b][t]][e] ----------------
__global__ void k_embed(const int* tokens, const float* emb, bf16_t* x_all) {
    int i = blockIdx.x * 256 + threadIdx.x;   // T*B*E
    int e = i & (E_ - 1);
    int b = (i >> 8) & 31;
    int t = i >> 13;
    int tok = tokens[b * T_ + t];
    x_all[(t * B_ + b) * E_ + e] = (bf16_t)emb[tok * E_ + e];
}

// ---------------- big GEMM (swizzled [outer][k] LDS, all-b128 fragment reads) --------
// MODE 0: A fp32 -> fp32 out (keys)
// MODE 1: A bf16 -> fp32 out remapped [B,T,V] (logits)
// MODE 2: A bf16 -> fp32 out plain (xk_all)
// LDS layout: As[row][koct^(row&7)] (128x64), Bs[col][koct^(col&7)] (128 cols x 64 k).
// XOR swizzle balances ds_read_b128 across the 8 16B slots per 128B row (8 lanes/slot).
template <int MODE>
__global__ __launch_bounds__(256) void k_gemm_big(const void* __restrict__ Av,
                                                  const float* __restrict__ Bm,
                                                  const float* __restrict__ bias,
                                                  float* __restrict__ outf,
                                                  int M, int N, int K) {
    __shared__ bf16_t As[128 * 64];
    __shared__ bf16_t Bs[128 * 64];
    const int tid = threadIdx.x;
    const int wave = tid >> 6, lane = tid & 63;
    const int quad = lane >> 4, l16 = lane & 15;
    const int m0 = blockIdx.x * 128, n0 = blockIdx.y * 128;
    const int wm = (wave >> 1) * 64, wn = (wave & 1) * 64;
    f32x4 acc[4][4] = {};
    for (int k0 = 0; k0 < K; k0 += 64) {
        __syncthreads();
        {
            // ---- A tile: 128 rows x 64 k ----
            for (int it = 0; it < 4; ++it) {
                int idx = it * 256 + tid;
                int r = idx >> 3, coct = idx & 7;          // 8 k-octs per row
                bf16x8 v;
                if (MODE == 0) {
                    const float* Ag = (const float*)Av + (long)m0 * K + k0;
                    v = cvt8(Ag + (long)r * K + coct * 8);
                } else {
                    const bf16_t* Ag = (const bf16_t*)Av + (long)m0 * K + k0;
                    v = *(const bf16x8*)(Ag + (long)r * K + coct * 8);
                }
                *(bf16x8*)&As[r * 64 + ((coct ^ (r & 7)) << 3)] = v;
            }
            // ---- B tile: 64 k x 128 cols, stored transposed [col][k] ----
            const float* Bg = Bm + (long)k0 * N + n0;
            for (int it = 0; it < 4; ++it) {
                int idx = it * 256 + tid;
                int col = idx & 127, koct = idx >> 7;      // 128 cols x (2 octs/iter)
                bf16x8 v;
                #pragma unroll
                for (int j = 0; j < 8; ++j)
                    v[j] = (bf16_t)Bg[(long)(koct * 8 + j) * N + col];  // coalesced across lanes
                *(bf16x8*)&Bs[col * 64 + ((koct ^ (col & 7)) << 3)] = v;
            }
        }
        __syncthreads();
        #pragma unroll
        for (int s = 0; s < 2; ++s) {
            const int c = (s << 2) + quad;                 // k-oct index 0..7
            bf16x8 af[4];
            #pragma unroll
            for (int mt = 0; mt < 4; ++mt)
                af[mt] = *(const bf16x8*)&As[(wm + mt * 16 + l16) * 64 + ((c ^ (l16 & 7)) << 3)];
            #pragma unroll
            for (int nt = 0; nt < 4; ++nt) {
                int col = wn + nt * 16 + l16;
                bf16x8 bfr = *(const bf16x8*)&Bs[col * 64 + ((c ^ (l16 & 7)) << 3)];
                #pragma unroll
                for (int mt = 0; mt < 4; ++mt)
                    acc[mt][nt] = __builtin_amdgcn_mfma_f32_16x16x32_bf16(af[mt], bfr, acc[mt][nt], 0, 0, 0);
            }
        }
    }
    for (int mt = 0; mt < 4; ++mt)
        for (int nt = 0; nt < 4; ++nt)
            for (int r = 0; r < 4; ++r) {
                int row = m0 + wm + mt * 16 + quad * 4 + r;
                int col = n0 + wn + nt * 16 + l16;
                float v = acc[mt][nt][r] + bias[col];
                if (MODE == 1) {
                    int t = row >> 5, b = row & 31;
                    outf[((long)(b * T_ + t)) * V_ + col] = v;
                } else {
                    outf[(long)row * N + col] = v;
                }
            }
}

// =====================================================================================
// Persistent cooperative decoder: entire T=64 loop in one kernel.
//   blocks 0..79  : hold [W1|Wr] col-tile (64 cols x 1024 k) bf16 in LDS  (phase 1)
//   blocks 80..143: hold Wk[256:1280] gate-tile (4 gates x 16 u x 1024 k) in LDS (phase 3)
//   blocks 0..31  : attention (score+softmax+ctx) per batch element      (phase 2)
// LDS weight layout: WT[col][k], k in 8-elem chunks at slot (k>>3)^(col&7)
// -> ds_read_b128 fragment reads balanced across bank groups.
// =====================================================================================
__global__ __launch_bounds__(256) void k_decode(
    const float* __restrict__ W1, const float* __restrict__ Wr, const float* __restrict__ Wk,
    const float* __restrict__ b1, const float* __restrict__ Va, const float* __restrict__ bv,
    const float* __restrict__ keys, const float* __restrict__ enc, const float* __restrict__ xk_all,
    float* __restrict__ q, float* __restrict__ zpart,
    bf16_t* __restrict__ h_bf, float* __restrict__ c_f,
    bf16_t* __restrict__ ctx_bf, bf16_t* __restrict__ h_all) {
    __shared__ bf16_t WT[64 * 1024];   // 128 KB weight tile
    __shared__ float scr[2048];        // qs[1024]+va[1024] (blocks<32) | zle[4][32][16] (blocks>=80)
    __shared__ float sw[128];          // scores / softmax weights

    const int bid = blockIdx.x, tid = threadIdx.x;
    const int wave = tid >> 6, lane = tid & 63;
    const int quad = lane >> 4, l16 = lane & 15;
    const int colw = (wave << 4) + l16;           // 0..63 tile-local column

    // ---- one-time LDS weight preload (own-block data only; no grid sync needed) ----
    if (bid < 80) {
        const int n0 = bid << 6;
        for (int it = 0; it < 64; ++it) {
            int idx = it * 256 + tid;             // 16384 float4 reads
            int k = idx >> 4, c4 = idx & 15;
            int col0 = c4 * 4;
            float4 v;
            if (n0 < 1024) v = *(const float4*)(W1 + (long)k * 1024 + n0 + col0);
            else           v = *(const float4*)(Wr + (long)k * 4096 + (n0 - 1024) + col0);
            float vv[4] = {v.x, v.y, v.z, v.w};
            for (int j = 0; j < 4; ++j) {
                int col = col0 + j;
                WT[(col << 10) + (((k >> 3) ^ (col & 7)) << 3) + (k & 7)] = (bf16_t)vv[j];
            }
        }
    } else {
        const int u0 = (bid - 80) << 4;
        for (int it = 0; it < 64; ++it) {
            int idx = it * 256 + tid;
            int k = idx >> 4, c4 = idx & 15;
            int col0 = c4 * 4;                    // tile col: gate = col>>4, u16 = col&15
            int g = col0 >> 4, c16 = col0 & 15;
            float4 v = *(const float4*)(Wk + (long)(256 + k) * 4096 + g * 1024 + u0 + c16);
            float vv[4] = {v.x, v.y, v.z, v.w};
            for (int j = 0; j < 4; ++j) {
                int col = col0 + j;
                WT[(col << 10) + (((k >> 3) ^ (col & 7)) << 3) + (k & 7)] = (bf16_t)vv[j];
            }
        }
    }
    if (bid < 32)
        for (int i = tid; i < 1024; i += 256) scr[1024 + i] = Va[i];   // va persistent
    __syncthreads();

    cg::grid_group grid = cg::this_grid();

    for (int t = 0; t < T_; ++t) {
        // ---------- phase 1: q = h@W1 + b1 ; zpart = h@Wr  (blocks 0..79) ----------
        if (bid < 80) {
            const int n0 = bid << 6;
            f32x4 acc[2] = {};
            #pragma unroll 4
            for (int k0 = 0; k0 < 1024; k0 += 64) {
                #pragma unroll
                for (int s = 0; s < 2; ++s) {
                    int koff = k0 + (s << 5) + (quad << 3);
                    bf16x8 a0 = *(const bf16x8*)(h_bf + (l16 << 10) + koff);
                    bf16x8 a1 = *(const bf16x8*)(h_bf + ((16 + l16) << 10) + koff);
                    int c = koff >> 3;
                    bf16x8 bfr = *(const bf16x8*)&WT[(colw << 10) + ((c ^ (colw & 7)) << 3)];
                    acc[0] = __builtin_amdgcn_mfma_f32_16x16x32_bf16(a0, bfr, acc[0], 0, 0, 0);
                    acc[1] = __builtin_amdgcn_mfma_f32_16x16x32_bf16(a1, bfr, acc[1], 0, 0, 0);
                }
            }
            const int col = n0 + colw;
            if (n0 < 1024) {
                float bb = b1[col];
                for (int mt = 0; mt < 2; ++mt)
                    for (int r = 0; r < 4; ++r) {
                        int row = mt * 16 + quad * 4 + r;
                        q[(row << 10) + col] = acc[mt][r] + bb;
                    }
            } else {
                for (int mt = 0; mt < 2; ++mt)
                    for (int r = 0; r < 4; ++r) {
                        int row = mt * 16 + quad * 4 + r;
                        zpart[(row << 12) + (col - 1024)] = acc[mt][r];
                    }
            }
        }
        grid.sync();

        // ---------- phase 2: scores -> softmax -> ctx  (blocks 0..31, one per b) ----------
        if (bid < 32) {
            const int b = bid;
            for (int i = tid; i < 1024; i += 256) scr[i] = q[(b << 10) + i];
            __syncthreads();
            {
                int s = tid >> 1, half = tid & 1;
                const float4* kp = (const float4*)(keys + (long)((b << 7) + s) * 1024 + (half << 9));
                const float* qp = scr + (half << 9);
                const float* vp = scr + 1024 + (half << 9);
                float p = 0.f;
                #pragma unroll 4
                for (int j = 0; j < 128; ++j) {
                    float4 kv = kp[j];
                    p += tanh_fast(qp[4 * j + 0] + kv.x) * vp[4 * j + 0];
                    p += tanh_fast(qp[4 * j + 1] + kv.y) * vp[4 * j + 1];
                    p += tanh_fast(qp[4 * j + 2] + kv.z) * vp[4 * j + 2];
                    p += tanh_fast(qp[4 * j + 3] + kv.w) * vp[4 * j + 3];
                }
                p += __shfl_down(p, 1);
                if (!half) sw[s] = p + bv[0];
            }
            __syncthreads();
            if (tid < 64) {
                float s0 = sw[tid], s1 = sw[tid + 64];
                float m = fmaxf(s0, s1);
                for (int off = 32; off; off >>= 1) m = fmaxf(m, __shfl_down(m, off));
                m = __shfl(m, 0);
                float e0 = expf(s0 - m), e1 = expf(s1 - m);
                float sum = e0 + e1;
                for (int off = 32; off; off >>= 1) sum += __shfl_down(sum, off);
                sum = __shfl(sum, 0);
                sw[tid] = e0 / sum;
                sw[tid + 64] = e1 / sum;
            }
            __syncthreads();
            {
                int u4 = tid << 2;                         // 256 threads x 4 u = 1024
                const float4* ep = (const float4*)(enc + ((long)b << 17) + u4);
                f32x4 a = {0.f, 0.f, 0.f, 0.f};
                #pragma unroll 8
                for (int s2 = 0; s2 < 128; ++s2) {
                    float4 v = ep[s2 << 8];                // stride 1024 floats
                    float wgt = sw[s2];
                    a[0] += wgt * v.x; a[1] += wgt * v.y;
                    a[2] += wgt * v.z; a[3] += wgt * v.w;
                }
                bf16_t* cp = ctx_bf + (b << 10) + u4;
                cp[0] = (bf16_t)a[0]; cp[1] = (bf16_t)a[1];
                cp[2] = (bf16_t)a[2]; cp[3] = (bf16_t)a[3];
            }
        }
        grid.sync();

        // ---------- phase 3: z = ctx@WkC + zpart + xk ; gates ; h,c  (blocks 80..143) ----------
        if (bid >= 80) {
            const int u0 = (bid - 80) << 4;
            f32x4 acc[2] = {};
            #pragma unroll 4
            for (int k0 = 0; k0 < 1024; k0 += 64) {
                #pragma unroll
                for (int s = 0; s < 2; ++s) {
                    int koff = k0 + (s << 5) + (quad << 3);
                    bf16x8 a0 = *(const bf16x8*)(ctx_bf + (l16 << 10) + koff);
                    bf16x8 a1 = *(const bf16x8*)(ctx_bf + ((16 + l16) << 10) + koff);
                    int c = koff >> 3;
                    bf16x8 bfr = *(const bf16x8*)&WT[(colw << 10) + ((c ^ (colw & 7)) << 3)];
                    acc[0] = __builtin_amdgcn_mfma_f32_16x16x32_bf16(a0, bfr, acc[0], 0, 0, 0);
                    acc[1] = __builtin_amdgcn_mfma_f32_16x16x32_bf16(a1, bfr, acc[1], 0, 0, 0);
                }
            }
            // exchange: zle[gate][b][u16]  (wave == gate)
            for (int mt = 0; mt < 2; ++mt)
                for (int r = 0; r < 4; ++r) {
                    int row = mt * 16 + quad * 4 + r;
                    scr[wave * 512 + row * 16 + l16] = acc[mt][r];
                }
            __syncthreads();
            for (int rep = 0; rep < 2; ++rep) {
                int oi = rep * 256 + tid;
                int b = oi >> 4, u = oi & 15;
                int ug = u0 + u;
                const float* xk = xk_all + ((long)((t << 5) + b) << 12);
                const float* zp = zpart + (b << 12);
                float zi = scr[0 * 512 + b * 16 + u] + zp[0 * 1024 + ug] + xk[0 * 1024 + ug];
                float zf = scr[1 * 512 + b * 16 + u] + zp[1 * 1024 + ug] + xk[1 * 1024 + ug];
                float zg = scr[2 * 512 + b * 16 + u] + zp[2 * 1024 + ug] + xk[2 * 1024 + ug];
                float zo = scr[3 * 512 + b * 16 + u] + zp[3 * 1024 + ug] + xk[3 * 1024 + ug];
                float cn = sigm(zf) * c_f[(b << 10) + ug] + sigm(zi) * tanhf(zg);
                float hn = sigm(zo) * tanhf(cn);
                c_f[(b << 10) + ug] = cn;
                bf16_t hb = (bf16_t)hn;
                h_bf[(b << 10) + ug] = hb;
                h_all[((long)((t << 5) + b) << 10) + ug] = hb;
            }
        }
        if (t + 1 < T_) grid.sync();   // h,c ready for next step
    }
}

extern "C" void kernel_launch(void* const* d_in, const int* in_sizes, int n_in,
                              void* d_out, int out_size, void* d_ws, size_t ws_size,
                              hipStream_t stream) {
    const int*   tokens = (const int*)d_in[0];
    const float* h0     = (const float*)d_in[1];
    const float* c0     = (const float*)d_in[2];
    const float* enc    = (const float*)d_in[3];
    const float* emb    = (const float*)d_in[4];
    const float* W1     = (const float*)d_in[5];
    const float* b1     = (const float*)d_in[6];
    const float* W2     = (const float*)d_in[7];
    const float* b2     = (const float*)d_in[8];
    const float* Va     = (const float*)d_in[9];
    const float* bv     = (const float*)d_in[10];
    const float* Wk     = (const float*)d_in[11];
    const float* Wr     = (const float*)d_in[12];
    const float* bl     = (const float*)d_in[13];
    const float* Wf     = (const float*)d_in[14];
    const float* bfv    = (const float*)d_in[15];

    char* ws = (char*)d_ws;
    float*  keys   = (float*)ws;  ws += 32 * 128 * 1024 * 4;   // 16.8 MB fp32
    float*  xk_all = (float*)ws;  ws += (size_t)2048 * 4096 * 4; // 33.6 MB fp32
    float*  q      = (float*)ws;  ws += 32 * 1024 * 4;
    float*  zpart  = (float*)ws;  ws += 32 * 4096 * 4;
    float*  c_f    = (float*)ws;  ws += 32 * 1024 * 4;
    bf16_t* ctx    = (bf16_t*)ws; ws += 32 * 1024 * 2;
    bf16_t* h_bf   = (bf16_t*)ws; ws += 32 * 1024 * 2;
    bf16_t* x_all  = (bf16_t*)ws; ws += 64 * 32 * 256 * 2;
    bf16_t* h_all  = (bf16_t*)ws; ws += 64 * 32 * 1024 * 2;
    float*  out    = (float*)d_out;

    k_init<<<128, 256, 0, stream>>>(h0, c0, h_bf, c_f);
    k_embed<<<2048, 256, 0, stream>>>(tokens, emb, x_all);
    // keys = enc @ W2 + b2   (M=4096, N=1024, K=1024) fp32 out
    k_gemm_big<0><<<dim3(32, 8), 256, 0, stream>>>(enc, W2, b2, keys, 4096, 1024, 1024);
    // xk_all = x_all @ Wk[0:256] + bl   (M=2048, N=4096, K=256) fp32 out — hoisted from loop
    k_gemm_big<2><<<dim3(16, 32), 256, 0, stream>>>(x_all, Wk, bl, xk_all, 2048, 4096, 256);

    // persistent cooperative decoder: whole T=64 loop, weights LDS-resident
    void* kargs[] = {(void*)&W1, (void*)&Wr, (void*)&Wk, (void*)&b1, (void*)&Va, (void*)&bv,
                     (void*)&keys, (void*)&enc, (void*)&xk_all, (void*)&q, (void*)&zpart,
                     (void*)&h_bf, (void*)&c_f, (void*)&ctx, (void*)&h_all};
    hipLaunchCooperativeKernel((void*)k_decode, dim3(NB_), dim3(256), kargs, 0, stream);

    // logits = h_all @ Wf + bf  (M=2048, N=32000, K=1024) remapped to [B,T,V]
    k_gemm_big<1><<<dim3(16, 250), 256, 0, stream>>>(h_all, Wf, bfv, out, 2048, 32000, 1024);
}

// Round 6
// 4930.648 us; speedup vs baseline: 1.4305x; 1.4305x over previous
//
#include <hip/hip_runtime.h>
#include <hip/hip_bf16.h>
#include <math.h>

#define B_ 32
#define T_ 64
#define S_ 128
#define V_ 32000
#define E_ 256
#define U_ 1024

#define NB_ 144   // 80 qz-tiles + 64 gate-tiles; blocks 0..31 also run attention

typedef __bf16 bf16_t;
typedef __bf16 bf16x8 __attribute__((ext_vector_type(8)));
typedef float f32x4 __attribute__((ext_vector_type(4)));

__device__ __forceinline__ float sigm(float x) { return 1.f / (1.f + expf(-x)); }
__device__ __forceinline__ float tanh_fast(float x) {
    float e = __expf(2.f * x);                 // inf-safe: e=inf -> 1 ; e=0 -> -1
    return 1.f - __fdividef(2.f, e + 1.f);
}

__device__ __forceinline__ bf16x8 cvt8(const float* p) {
    float4 f0 = *(const float4*)p;
    float4 f1 = *(const float4*)(p + 4);
    bf16x8 v;
    v[0] = (bf16_t)f0.x; v[1] = (bf16_t)f0.y; v[2] = (bf16_t)f0.z; v[3] = (bf16_t)f0.w;
    v[4] = (bf16_t)f1.x; v[5] = (bf16_t)f1.y; v[6] = (bf16_t)f1.z; v[7] = (bf16_t)f1.w;
    return v;
}

// ---- lightweight device-scope semaphores (monotonic counters, zeroed in k_init) ----
__device__ __forceinline__ void sem_arrive(unsigned* c) {
    __syncthreads();                            // all block writes done
    if (threadIdx.x == 0)
        __hip_atomic_fetch_add(c, 1u, __ATOMIC_RELEASE, __HIP_MEMORY_SCOPE_AGENT);
}
__device__ __forceinline__ void sem_wait(unsigned* c, unsigned target) {
    if (threadIdx.x == 0) {
        while (__hip_atomic_load(c, __ATOMIC_RELAXED, __HIP_MEMORY_SCOPE_AGENT) < target)
            __builtin_amdgcn_s_sleep(8);        // backoff: don't storm the coherence point
        __builtin_amdgcn_fence(__ATOMIC_ACQUIRE, "agent");
    }
    __syncthreads();
}

// ---------------- init: h,c from h0,c0 ; zero semaphores ----------------
__global__ void k_init(const float* h0, const float* c0, bf16_t* h_bf, float* c_f,
                       unsigned* sems) {
    int i = blockIdx.x * 256 + threadIdx.x;   // 32*1024
    h_bf[i] = (bf16_t)h0[i];
    c_f[i] = c0[i];
    if (blockIdx.x == 0 && threadIdx.x < 128) sems[threadIdx.x] = 0;
}

// ---------------- embed: x_all[t][b][e] = emb[tokens[b][t]][e] ----------------
__global__ void k_embed(const int* tokens, const float* emb, bf16_t* x_all) {
    int i = blockIdx.x * 256 + threadIdx.x;   // T*B*E
    int e = i & (E_ - 1);
    int b = (i >> 8) & 31;
    int t = i >> 13;
    int tok = tokens[b * T_ + t];
    x_all[(t * B_ + b) * E_ + e] = (bf16_t)emb[tok * E_ + e];
}

// ---------------- Wf transpose+cvt: WfT[v][k] (bf16) from Wf[k][v] (fp32) ----------------
// 64x64 tiles via LDS (65-float stride: conflict-free both directions), coalesced I/O.
__global__ __launch_bounds__(256) void k_cvt_wf(const float* __restrict__ Wf,
                                                bf16_t* __restrict__ WfT) {
    __shared__ float tile[64][65];
    const int v0 = blockIdx.x << 6, k0 = blockIdx.y << 6;
    const int tid = threadIdx.x;
    #pragma unroll
    for (int it = 0; it < 16; ++it) {
        int idx = it * 256 + tid;
        int r = idx >> 6, c = idx & 63;        // r = k-local, c = v-local
        tile[r][c] = Wf[(long)(k0 + r) * V_ + v0 + c];
    }
    __syncthreads();
    #pragma unroll
    for (int it = 0; it < 16; ++it) {
        int idx = it * 256 + tid;
        int r = idx >> 6, c = idx & 63;        // r = v-local, c = k-local
        WfT[(long)(v0 + r) * U_ + k0 + c] = (bf16_t)tile[c][r];
    }
}

// ---------------- big GEMM (swizzled [outer][k] LDS, all-b128 fragment reads) --------
// MODE 0: A fp32, B fp32 [K][N] -> fp32 out (keys)
// MODE 1: A bf16, B fp32 [K][N] -> fp32 out remapped [B,T,V] (logits fallback)
// MODE 2: A bf16, B fp32 [K][N] -> fp32 out plain (xk_all)
// MODE 3: A bf16, B bf16 [N][K] pre-transposed -> fp32 out remapped [B,T,V] (logits)
template <int MODE>
__global__ __launch_bounds__(256) void k_gemm_big(const void* __restrict__ Av,
                                                  const void* __restrict__ Bv,
                                                  const float* __restrict__ bias,
                                                  float* __restrict__ outf,
                                                  int M, int N, int K) {
    __shared__ bf16_t As[128 * 64];
    __shared__ bf16_t Bs[128 * 64];
    const int tid = threadIdx.x;
    const int wave = tid >> 6, lane = tid & 63;
    const int quad = lane >> 4, l16 = lane & 15;
    const int m0 = blockIdx.x * 128, n0 = blockIdx.y * 128;
    const int wm = (wave >> 1) * 64, wn = (wave & 1) * 64;
    f32x4 acc[4][4] = {};
    for (int k0 = 0; k0 < K; k0 += 64) {
        __syncthreads();
        {
            // ---- A tile: 128 rows x 64 k ----
            for (int it = 0; it < 4; ++it) {
                int idx = it * 256 + tid;
                int r = idx >> 3, coct = idx & 7;
                bf16x8 v;
                if (MODE == 0) {
                    const float* Ag = (const float*)Av + (long)m0 * K + k0;
                    v = cvt8(Ag + (long)r * K + coct * 8);
                } else {
                    const bf16_t* Ag = (const bf16_t*)Av + (long)m0 * K + k0;
                    v = *(const bf16x8*)(Ag + (long)r * K + coct * 8);
                }
                *(bf16x8*)&As[r * 64 + ((coct ^ (r & 7)) << 3)] = v;
            }
            // ---- B tile: 128 cols x 64 k, stored [col][k] ----
            if (MODE == 3) {
                const bf16_t* Bg = (const bf16_t*)Bv;   // [N][K] bf16
                for (int it = 0; it < 4; ++it) {
                    int idx = it * 256 + tid;
                    int col = idx >> 3, coct = idx & 7;
                    bf16x8 v = *(const bf16x8*)(Bg + (long)(n0 + col) * K + k0 + coct * 8);
                    *(bf16x8*)&Bs[col * 64 + ((coct ^ (col & 7)) << 3)] = v;
                }
            } else {
                const float* Bg = (const float*)Bv + (long)k0 * N + n0;  // [K][N] fp32
                for (int it = 0; it < 4; ++it) {
                    int idx = it * 256 + tid;
                    int col = idx & 127, koct = idx >> 7;
                    bf16x8 v;
                    #pragma unroll
                    for (int j = 0; j < 8; ++j)
                        v[j] = (bf16_t)Bg[(long)(koct * 8 + j) * N + col];  // coalesced across lanes
                    *(bf16x8*)&Bs[col * 64 + ((koct ^ (col & 7)) << 3)] = v;
                }
            }
        }
        __syncthreads();
        #pragma unroll
        for (int s = 0; s < 2; ++s) {
            const int c = (s << 2) + quad;
            bf16x8 af[4];
            #pragma unroll
            for (int mt = 0; mt < 4; ++mt)
                af[mt] = *(const bf16x8*)&As[(wm + mt * 16 + l16) * 64 + ((c ^ (l16 & 7)) << 3)];
            #pragma unroll
            for (int nt = 0; nt < 4; ++nt) {
                int col = wn + nt * 16 + l16;
                bf16x8 bfr = *(const bf16x8*)&Bs[col * 64 + ((c ^ (l16 & 7)) << 3)];
                #pragma unroll
                for (int mt = 0; mt < 4; ++mt)
                    acc[mt][nt] = __builtin_amdgcn_mfma_f32_16x16x32_bf16(af[mt], bfr, acc[mt][nt], 0, 0, 0);
            }
        }
    }
    for (int mt = 0; mt < 4; ++mt)
        for (int nt = 0; nt < 4; ++nt)
            for (int r = 0; r < 4; ++r) {
                int row = m0 + wm + mt * 16 + quad * 4 + r;
                int col = n0 + wn + nt * 16 + l16;
                float v = acc[mt][nt][r] + bias[col];
                if (MODE == 1 || MODE == 3) {
                    int t = row >> 5, b = row & 31;
                    outf[((long)(b * T_ + t)) * V_ + col] = v;
                } else {
                    outf[(long)row * N + col] = v;
                }
            }
}

// =====================================================================================
// Persistent decoder with producer/consumer semaphores instead of full grid barriers.
//   blocks 0..15 : q cols      -> arrive sem1 (16)
//   blocks 0..31 : wait sem1 -> attention -> arrive sem2
//   blocks 16..79: zpart; 32..79 arrive sem2 right after (overlaps attention)  (80 total)
//   blocks 80..143: wait sem2 -> gates -> arrive sem3 (64)
//   blocks 0..79 : wait sem3 before next step's phase 1
// =====================================================================================
__global__ __launch_bounds__(256) void k_decode(
    const float* __restrict__ W1, const float* __restrict__ Wr, const float* __restrict__ Wk,
    const float* __restrict__ b1, const float* __restrict__ Va, const float* __restrict__ bv,
    const float* __restrict__ keys, const float* __restrict__ enc, const float* __restrict__ xk_all,
    float* __restrict__ q, float* __restrict__ zpart,
    bf16_t* __restrict__ h_bf, float* __restrict__ c_f,
    bf16_t* __restrict__ ctx_bf, bf16_t* __restrict__ h_all,
    unsigned* __restrict__ sems) {
    __shared__ bf16_t WT[64 * 1024];   // 128 KB weight tile
    __shared__ float scr[2048];        // qs[1024]+va[1024] (blocks<32) | zle[4][32][16] (blocks>=80)
    __shared__ float sw[128];          // scores / softmax weights

    unsigned* sem1 = sems;             // q ready        (16 arrivals/step)
    unsigned* sem2 = sems + 32;        // ctx+zpart ready (80 arrivals/step)
    unsigned* sem3 = sems + 64;        // h,c ready      (64 arrivals/step)

    const int bid = blockIdx.x, tid = threadIdx.x;
    const int wave = tid >> 6, lane = tid & 63;
    const int quad = lane >> 4, l16 = lane & 15;
    const int colw = (wave << 4) + l16;           // 0..63 tile-local column

    // ---- one-time LDS weight preload (own-block data only) ----
    if (bid < 80) {
        const int n0 = bid << 6;
        for (int it = 0; it < 64; ++it) {
            int idx = it * 256 + tid;
            int k = idx >> 4, c4 = idx & 15;
            int col0 = c4 * 4;
            float4 v;
            if (n0 < 1024) v = *(const float4*)(W1 + (long)k * 1024 + n0 + col0);
            else           v = *(const float4*)(Wr + (long)k * 4096 + (n0 - 1024) + col0);
            float vv[4] = {v.x, v.y, v.z, v.w};
            for (int j = 0; j < 4; ++j) {
                int col = col0 + j;
                WT[(col << 10) + (((k >> 3) ^ (col & 7)) << 3) + (k & 7)] = (bf16_t)vv[j];
            }
        }
    } else {
        const int u0 = (bid - 80) << 4;
        for (int it = 0; it < 64; ++it) {
            int idx = it * 256 + tid;
            int k = idx >> 4, c4 = idx & 15;
            int col0 = c4 * 4;
            int g = col0 >> 4, c16 = col0 & 15;
            float4 v = *(const float4*)(Wk + (long)(256 + k) * 4096 + g * 1024 + u0 + c16);
            float vv[4] = {v.x, v.y, v.z, v.w};
            for (int j = 0; j < 4; ++j) {
                int col = col0 + j;
                WT[(col << 10) + (((k >> 3) ^ (col & 7)) << 3) + (k & 7)] = (bf16_t)vv[j];
            }
        }
    }
    if (bid < 32)
        for (int i = tid; i < 1024; i += 256) scr[1024 + i] = Va[i];   // va persistent
    __syncthreads();

    for (int t = 0; t < T_; ++t) {
        const unsigned g = (unsigned)(t + 1);
        if (bid < 80) {
            // ---------- phase 1: q = h@W1 + b1 ; zpart = h@Wr ----------
            const int n0 = bid << 6;
            f32x4 acc[2] = {};
            #pragma unroll 4
            for (int k0 = 0; k0 < 1024; k0 += 64) {
                #pragma unroll
                for (int s = 0; s < 2; ++s) {
                    int koff = k0 + (s << 5) + (quad << 3);
                    bf16x8 a0 = *(const bf16x8*)(h_bf + (l16 << 10) + koff);
                    bf16x8 a1 = *(const bf16x8*)(h_bf + ((16 + l16) << 10) + koff);
                    int c = koff >> 3;
                    bf16x8 bfr = *(const bf16x8*)&WT[(colw << 10) + ((c ^ (colw & 7)) << 3)];
                    acc[0] = __builtin_amdgcn_mfma_f32_16x16x32_bf16(a0, bfr, acc[0], 0, 0, 0);
                    acc[1] = __builtin_amdgcn_mfma_f32_16x16x32_bf16(a1, bfr, acc[1], 0, 0, 0);
                }
            }
            const int col = n0 + colw;
            if (n0 < 1024) {
                float bb = b1[col];
                for (int mt = 0; mt < 2; ++mt)
                    for (int r = 0; r < 4; ++r) {
                        int row = mt * 16 + quad * 4 + r;
                        q[(row << 10) + col] = acc[mt][r] + bb;
                    }
            } else {
                for (int mt = 0; mt < 2; ++mt)
                    for (int r = 0; r < 4; ++r) {
                        int row = mt * 16 + quad * 4 + r;
                        zpart[(row << 12) + (col - 1024)] = acc[mt][r];
                    }
            }

            if (bid < 16) sem_arrive(sem1);

            if (bid < 32) {
                // ---------- phase 2: scores -> softmax -> ctx (one block per b) ----------
                sem_wait(sem1, g * 16u);
                const int b = bid;
                for (int i = tid; i < 1024; i += 256) scr[i] = q[(b << 10) + i];
                __syncthreads();
                {
                    int s = tid >> 1, half = tid & 1;
                    const float4* kp = (const float4*)(keys + (long)((b << 7) + s) * 1024 + (half << 9));
                    const float* qp = scr + (half << 9);
                    const float* vp = scr + 1024 + (half << 9);
                    float p = 0.f;
                    #pragma unroll 4
                    for (int j = 0; j < 128; ++j) {
                        float4 kv = kp[j];
                        p += tanh_fast(qp[4 * j + 0] + kv.x) * vp[4 * j + 0];
                        p += tanh_fast(qp[4 * j + 1] + kv.y) * vp[4 * j + 1];
                        p += tanh_fast(qp[4 * j + 2] + kv.z) * vp[4 * j + 2];
                        p += tanh_fast(qp[4 * j + 3] + kv.w) * vp[4 * j + 3];
                    }
                    p += __shfl_down(p, 1);
                    if (!half) sw[s] = p + bv[0];
                }
                __syncthreads();
                if (tid < 64) {
                    float s0 = sw[tid], s1 = sw[tid + 64];
                    float m = fmaxf(s0, s1);
                    for (int off = 32; off; off >>= 1) m = fmaxf(m, __shfl_down(m, off));
                    m = __shfl(m, 0);
                    float e0 = expf(s0 - m), e1 = expf(s1 - m);
                    float sum = e0 + e1;
                    for (int off = 32; off; off >>= 1) sum += __shfl_down(sum, off);
                    sum = __shfl(sum, 0);
                    sw[tid] = e0 / sum;
                    sw[tid + 64] = e1 / sum;
                }
                __syncthreads();
                {
                    int u4 = tid << 2;
                    const float4* ep = (const float4*)(enc + ((long)b << 17) + u4);
                    f32x4 a = {0.f, 0.f, 0.f, 0.f};
                    #pragma unroll 8
                    for (int s2 = 0; s2 < 128; ++s2) {
                        float4 v = ep[s2 << 8];
                        float wgt = sw[s2];
                        a[0] += wgt * v.x; a[1] += wgt * v.y;
                        a[2] += wgt * v.z; a[3] += wgt * v.w;
                    }
                    bf16_t* cp = ctx_bf + (b << 10) + u4;
                    cp[0] = (bf16_t)a[0]; cp[1] = (bf16_t)a[1];
                    cp[2] = (bf16_t)a[2]; cp[3] = (bf16_t)a[3];
                }
                sem_arrive(sem2);
            } else {
                sem_arrive(sem2);   // zpart done; overlaps attention
            }
            if (t + 1 < T_) sem_wait(sem3, g * 64u);
        } else {
            // ---------- phase 3: z = ctx@WkC + zpart + xk ; gates ; h,c ----------
            sem_wait(sem2, g * 80u);
            const int u0 = (bid - 80) << 4;
            f32x4 acc[2] = {};
            #pragma unroll 4
            for (int k0 = 0; k0 < 1024; k0 += 64) {
                #pragma unroll
                for (int s = 0; s < 2; ++s) {
                    int koff = k0 + (s << 5) + (quad << 3);
                    bf16x8 a0 = *(const bf16x8*)(ctx_bf + (l16 << 10) + koff);
                    bf16x8 a1 = *(const bf16x8*)(ctx_bf + ((16 + l16) << 10) + koff);
                    int c = koff >> 3;
                    bf16x8 bfr = *(const bf16x8*)&WT[(colw << 10) + ((c ^ (colw & 7)) << 3)];
                    acc[0] = __builtin_amdgcn_mfma_f32_16x16x32_bf16(a0, bfr, acc[0], 0, 0, 0);
                    acc[1] = __builtin_amdgcn_mfma_f32_16x16x32_bf16(a1, bfr, acc[1], 0, 0, 0);
                }
            }
            // exchange: zle[gate][b][u16]  (wave == gate)
            for (int mt = 0; mt < 2; ++mt)
                for (int r = 0; r < 4; ++r) {
                    int row = mt * 16 + quad * 4 + r;
                    scr[wave * 512 + row * 16 + l16] = acc[mt][r];
                }
            __syncthreads();
            for (int rep = 0; rep < 2; ++rep) {
                int oi = rep * 256 + tid;
                int b = oi >> 4, u = oi & 15;
                int ug = u0 + u;
                const float* xk = xk_all + ((long)((t << 5) + b) << 12);
                const float* zp = zpart + (b << 12);
                float zi = scr[0 * 512 + b * 16 + u] + zp[0 * 1024 + ug] + xk[0 * 1024 + ug];
                float zf = scr[1 * 512 + b * 16 + u] + zp[1 * 1024 + ug] + xk[1 * 1024 + ug];
                float zg = scr[2 * 512 + b * 16 + u] + zp[2 * 1024 + ug] + xk[2 * 1024 + ug];
                float zo = scr[3 * 512 + b * 16 + u] + zp[3 * 1024 + ug] + xk[3 * 1024 + ug];
                float cn = sigm(zf) * c_f[(b << 10) + ug] + sigm(zi) * tanhf(zg);
                float hn = sigm(zo) * tanhf(cn);
                c_f[(b << 10) + ug] = cn;
                bf16_t hb = (bf16_t)hn;
                h_bf[(b << 10) + ug] = hb;
                h_all[((long)((t << 5) + b) << 10) + ug] = hb;
            }
            sem_arrive(sem3);
        }
    }
}

extern "C" void kernel_launch(void* const* d_in, const int* in_sizes, int n_in,
                              void* d_out, int out_size, void* d_ws, size_t ws_size,
                              hipStream_t stream) {
    const int*   tokens = (const int*)d_in[0];
    const float* h0     = (const float*)d_in[1];
    const float* c0     = (const float*)d_in[2];
    const float* enc    = (const float*)d_in[3];
    const float* emb    = (const float*)d_in[4];
    const float* W1     = (const float*)d_in[5];
    const float* b1     = (const float*)d_in[6];
    const float* W2     = (const float*)d_in[7];
    const float* b2     = (const float*)d_in[8];
    const float* Va     = (const float*)d_in[9];
    const float* bv     = (const float*)d_in[10];
    const float* Wk     = (const float*)d_in[11];
    const float* Wr     = (const float*)d_in[12];
    const float* bl     = (const float*)d_in[13];
    const float* Wf     = (const float*)d_in[14];
    const float* bfv    = (const float*)d_in[15];

    char* ws = (char*)d_ws;
    char* ws0 = ws;
    float*  keys   = (float*)ws;  ws += 32 * 128 * 1024 * 4;     // 16.8 MB fp32
    float*  xk_all = (float*)ws;  ws += (size_t)2048 * 4096 * 4; // 33.6 MB fp32
    float*  q      = (float*)ws;  ws += 32 * 1024 * 4;
    float*  zpart  = (float*)ws;  ws += 32 * 4096 * 4;
    float*  c_f    = (float*)ws;  ws += 32 * 1024 * 4;
    bf16_t* ctx    = (bf16_t*)ws; ws += 32 * 1024 * 2;
    bf16_t* h_bf   = (bf16_t*)ws; ws += 32 * 1024 * 2;
    bf16_t* x_all  = (bf16_t*)ws; ws += 64 * 32 * 256 * 2;
    bf16_t* h_all  = (bf16_t*)ws; ws += 64 * 32 * 1024 * 2;
    unsigned* sems = (unsigned*)ws; ws += 128 * 4;
    bf16_t* WfT    = (bf16_t*)ws; ws += (size_t)V_ * U_ * 2;     // 65.5 MB (optional)
    const bool useWfT = ((size_t)(ws - ws0) <= ws_size);
    float*  out    = (float*)d_out;

    k_init<<<128, 256, 0, stream>>>(h0, c0, h_bf, c_f, sems);
    k_embed<<<2048, 256, 0, stream>>>(tokens, emb, x_all);
    if (useWfT)  // Wf -> bf16, transposed [V][K]: halves logits-GEMM B traffic, linear staging
        k_cvt_wf<<<dim3(500, 16), 256, 0, stream>>>(Wf, WfT);
    // keys = enc @ W2 + b2   (M=4096, N=1024, K=1024) fp32 out
    k_gemm_big<0><<<dim3(32, 8), 256, 0, stream>>>(enc, W2, b2, keys, 4096, 1024, 1024);
    // xk_all = x_all @ Wk[0:256] + bl   (M=2048, N=4096, K=256) fp32 out — hoisted from loop
    k_gemm_big<2><<<dim3(16, 32), 256, 0, stream>>>(x_all, Wk, bl, xk_all, 2048, 4096, 256);

    // persistent decoder: whole T=64 loop, weights LDS-resident, semaphore sync
    void* kargs[] = {(void*)&W1, (void*)&Wr, (void*)&Wk, (void*)&b1, (void*)&Va, (void*)&bv,
                     (void*)&keys, (void*)&enc, (void*)&xk_all, (void*)&q, (void*)&zpart,
                     (void*)&h_bf, (void*)&c_f, (void*)&ctx, (void*)&h_all, (void*)&sems};
    hipLaunchCooperativeKernel((void*)k_decode, dim3(NB_), dim3(256), kargs, 0, stream);

    // logits = h_all @ Wf + bf  (M=2048, N=32000, K=1024) remapped to [B,T,V]
    if (useWfT)
        k_gemm_big<3><<<dim3(16, 250), 256, 0, stream>>>(h_all, WfT, bfv, out, 2048, 32000, 1024);
    else
        k_gemm_big<1><<<dim3(16, 250), 256, 0, stream>>>(h_all, Wf, bfv, out, 2048, 32000, 1024);
}